// Round 1
// baseline (2282.517 us; speedup 1.0000x reference)
//
#include <hip/hip_runtime.h>
#include <math.h>

#define B_ 256
#define T_ 576
#define FT_ 24
#define M_ 32
#define H_ 256
#define E_ 512
#define KX_ 544   // E + M
#define G_ 1024   // 4H
#define ND_ 2048  // 2*4H
#define EPS_ 1e-6f

typedef __attribute__((ext_vector_type(8))) short bf8;   // 8 bf16 in 4 VGPRs
typedef __attribute__((ext_vector_type(4))) float f4;

__device__ __forceinline__ float bf2f(unsigned short s) {
    union { unsigned u; float f; } c; c.u = ((unsigned)s) << 16; return c.f;
}
__device__ __forceinline__ short f2bf(float f) {
    union { float f; unsigned u; } c; c.f = f;
    unsigned r = c.u + 0x7fffu + ((c.u >> 16) & 1u);   // round-to-nearest-even
    return (short)(r >> 16);
}
__device__ __forceinline__ float sigm(float x) { return 1.f / (1.f + expf(-x)); }

// ---------------- alpha: period-similarity softmax weights [B,24] ----------------
__global__ __launch_bounds__(64) void k_alpha(const float* __restrict__ ff,
                                              const float* __restrict__ fhist,
                                              float* __restrict__ alpha) {
    int b = blockIdx.x;
    int t = threadIdx.x;          // lanes 0..23 active for compute
    float dp = 0.f;
    if (t < 24) {
        float fv[M_];
        const float* fp = ff + (b * FT_ + t) * M_;
        #pragma unroll
        for (int m = 0; m < M_; m++) fv[m] = fp[m];
        float dist = 0.f;
        for (int p = 0; p < 24; p++) {
            const float* hp = fhist + (b * T_ + p * 24 + t) * M_;
            float s = 0.f;
            #pragma unroll
            for (int m = 0; m < M_; m++) { float d = fv[m] - hp[m] + EPS_; s += d * d; }
            dist += sqrtf(s);
        }
        dp = 1.f / dist;
    }
    float v = (t < 24) ? dp : -INFINITY;
    float mx = v;
    for (int off = 32; off; off >>= 1) mx = fmaxf(mx, __shfl_xor(mx, off));
    float e = (t < 24) ? expf(dp - mx) : 0.f;
    float sm = e;
    for (int off = 32; off; off >>= 1) sm += __shfl_xor(sm, off);
    if (t < 24) alpha[b * 24 + t] = e / sm;
}

// ---------------- fp32 -> bf16 cast, 4 elems/thread ----------------
__global__ __launch_bounds__(256) void k_cast4(const float* __restrict__ src,
                                               short* __restrict__ dst, int n4) {
    int i = blockIdx.x * 256 + threadIdx.x;
    if (i < n4) {
        float4 v = ((const float4*)src)[i];
        short4 o;
        o.x = f2bf(v.x); o.y = f2bf(v.y); o.z = f2bf(v.z); o.w = f2bf(v.w);
        ((short4*)dst)[i] = o;
    }
}

// ---------------- init: x0 = [h0|h1|ff0] bf16, h bf16, c fp32 ----------------
__global__ __launch_bounds__(256) void k_init(const float* __restrict__ hidden,
                                              const float* __restrict__ cell,
                                              const float* __restrict__ ff,
                                              short* __restrict__ x, short* __restrict__ hb,
                                              float* __restrict__ c) {
    int i = blockIdx.x * 256 + threadIdx.x;   // [0, 2*256*256)
    int d = i >> 16, b = (i >> 8) & 255, j = i & 255;
    float h = hidden[i];
    short hv = f2bf(h);
    hb[i] = hv;
    x[b * KX_ + d * H_ + j] = hv;
    c[i] = cell[i];
    if (d == 0 && j < M_) x[b * KX_ + E_ + j] = f2bf(ff[(b * FT_ + 0) * M_ + j]);
}

// ---------------- generic bf16 MFMA GEMM: C[256 x N] = act(A[256xK] * W[NxK]^T + bias) ----------------
// EPI: 0 = tanh -> bf16 out; 1 = +bias fp32 out; 3 = relu fp32 out
template <int EPI>
__global__ __launch_bounds__(256) void k_gemm(const short* __restrict__ A, int lda, int K,
                                              const short* __restrict__ W,
                                              const float* __restrict__ bias,
                                              void* __restrict__ out, int ldc) {
    __shared__ short As[64][40];
    __shared__ short Bs[64][40];
    int n0 = blockIdx.x * 64, m0 = blockIdx.y * 64;
    int tid = threadIdx.x, lane = tid & 63, w = tid >> 6;
    int wm = (w & 1) * 32, wn = (w >> 1) * 32;
    int r = tid >> 2, cg = (tid & 3) * 8;
    f4 acc[2][2] = {};
    int nch = K / 32;
    int4 pa = *(const int4*)(A + (m0 + r) * lda + cg);
    int4 pb = *(const int4*)(W + (n0 + r) * K + cg);
    for (int kc = 0; kc < nch; kc++) {
        *(int4*)&As[r][cg] = pa;
        *(int4*)&Bs[r][cg] = pb;
        __syncthreads();
        if (kc + 1 < nch) {
            int ko = (kc + 1) * 32 + cg;
            pa = *(const int4*)(A + (m0 + r) * lda + ko);
            pb = *(const int4*)(W + (n0 + r) * K + ko);
        }
        int fr = lane & 15, fk = (lane >> 4) * 8;
        bf8 a0 = *(const bf8*)&As[wm + fr][fk];
        bf8 a1 = *(const bf8*)&As[wm + 16 + fr][fk];
        bf8 b0 = *(const bf8*)&Bs[wn + fr][fk];
        bf8 b1 = *(const bf8*)&Bs[wn + 16 + fr][fk];
        acc[0][0] = __builtin_amdgcn_mfma_f32_16x16x32_bf16(a0, b0, acc[0][0], 0, 0, 0);
        acc[0][1] = __builtin_amdgcn_mfma_f32_16x16x32_bf16(a0, b1, acc[0][1], 0, 0, 0);
        acc[1][0] = __builtin_amdgcn_mfma_f32_16x16x32_bf16(a1, b0, acc[1][0], 0, 0, 0);
        acc[1][1] = __builtin_amdgcn_mfma_f32_16x16x32_bf16(a1, b1, acc[1][1], 0, 0, 0);
        __syncthreads();
    }
    int colb = n0 + wn + (lane & 15);
    int rowb = m0 + wm + (lane >> 4) * 4;
    #pragma unroll
    for (int im = 0; im < 2; im++)
        #pragma unroll
        for (int in = 0; in < 2; in++) {
            int col = colb + in * 16;
            float bv = bias[col];
            #pragma unroll
            for (int q = 0; q < 4; q++) {
                int row = rowb + im * 16 + q;
                float v = acc[im][in][q] + bv;
                if (EPI == 0)      ((short*)out)[row * ldc + col] = f2bf(tanhf(v));
                else if (EPI == 1) ((float*)out)[row * ldc + col] = v;
                else               ((float*)out)[row * ldc + col] = fmaxf(v, 0.f);
            }
        }
}

// ---------------- softmax(logits)*alpha then weighted sum over enc, 4 t-slices/b ----------------
template <int BF16E>
__global__ __launch_bounds__(256) void k_ctx(const float* __restrict__ logits,
                                             const float* __restrict__ alpha,
                                             const short* __restrict__ encb,
                                             const float* __restrict__ encf,
                                             float* __restrict__ ctxp) {
    int b = blockIdx.x >> 2, s = blockIdx.x & 3;
    int tid = threadIdx.x;
    __shared__ float wt[T_];
    __shared__ float red[4];
    const float* lg = logits + b * T_;
    float l0 = lg[tid], l1 = lg[tid + 256];
    float l2 = (tid < 64) ? lg[tid + 512] : -INFINITY;
    float mx = fmaxf(fmaxf(l0, l1), l2);
    for (int off = 32; off; off >>= 1) mx = fmaxf(mx, __shfl_xor(mx, off));
    if ((tid & 63) == 0) red[tid >> 6] = mx;
    __syncthreads();
    mx = fmaxf(fmaxf(red[0], red[1]), fmaxf(red[2], red[3]));
    float e0 = expf(l0 - mx), e1 = expf(l1 - mx);
    float e2 = (tid < 64) ? expf(l2 - mx) : 0.f;
    float sm = e0 + e1 + e2;
    for (int off = 32; off; off >>= 1) sm += __shfl_xor(sm, off);
    __syncthreads();
    if ((tid & 63) == 0) red[tid >> 6] = sm;
    __syncthreads();
    float inv = 1.f / (red[0] + red[1] + red[2] + red[3]);
    const float* al = alpha + b * 24;
    wt[tid]       = e0 * inv * al[tid / 24];
    wt[tid + 256] = e1 * inv * al[(tid + 256) / 24];
    if (tid < 64) wt[tid + 512] = e2 * inv * al[(tid + 512) / 24];
    __syncthreads();
    float a0 = 0.f, a1 = 0.f;
    int t0 = s * (T_ / 4);
    if (BF16E) {
        const unsigned* ep = (const unsigned*)(encb + (b * T_ + t0) * E_) + tid;
        for (int t = 0; t < T_ / 4; t++) {
            float wv = wt[t0 + t];
            unsigned u = ep[t * (E_ / 2)];
            a0 += wv * bf2f((unsigned short)(u & 0xffffu));
            a1 += wv * bf2f((unsigned short)(u >> 16));
        }
    } else {
        const float2* ep = (const float2*)(encf + ((size_t)b * T_ + t0) * E_) + tid;
        for (int t = 0; t < T_ / 4; t++) {
            float wv = wt[t0 + t];
            float2 u = ep[t * (E_ / 2)];
            a0 += wv * u.x;
            a1 += wv * u.y;
        }
    }
    float* cp = ctxp + (s * B_ + b) * E_;
    cp[2 * tid] = a0;
    cp[2 * tid + 1] = a1;
}

// ---------------- gates GEMM: [256 x 2048] = inp*Wih^T + h[d]*Whh^T ----------------
__global__ __launch_bounds__(256) void k_gates(const float* __restrict__ ctxp,
                                               const float* __restrict__ ff, int step,
                                               const short* __restrict__ hb,
                                               const short* __restrict__ Wih,
                                               const short* __restrict__ Whh,
                                               float* __restrict__ gates) {
    __shared__ short As[64][40];
    __shared__ short Bs[64][40];
    int n0 = blockIdx.x * 64, m0 = blockIdx.y * 64;
    int tid = threadIdx.x, lane = tid & 63, w = tid >> 6;
    int wm = (w & 1) * 32, wn = (w >> 1) * 32;
    int r = tid >> 2, cg = (tid & 3) * 8;
    int b = m0 + r;
    f4 acc[2][2] = {};
    int fr = lane & 15, fk = (lane >> 4) * 8;
    // phase 1: inp = [ctx(sum of 4 partials) | ff_t], K = 544
    for (int kc = 0; kc < KX_ / 32; kc++) {
        int k = kc * 32 + cg;
        short av[8];
        if (k < E_) {
            const float* c0 = ctxp + b * E_ + k;
            #pragma unroll
            for (int j = 0; j < 8; j++) {
                float v = c0[j] + c0[B_ * E_ + j] + c0[2 * B_ * E_ + j] + c0[3 * B_ * E_ + j];
                av[j] = f2bf(v);
            }
        } else {
            const float* fp = ff + (b * FT_ + step) * M_ + (k - E_);
            #pragma unroll
            for (int j = 0; j < 8; j++) av[j] = f2bf(fp[j]);
        }
        *(int4*)&As[r][cg] = *(int4*)av;
        *(int4*)&Bs[r][cg] = *(const int4*)(Wih + (n0 + r) * KX_ + k);
        __syncthreads();
        bf8 a0 = *(const bf8*)&As[wm + fr][fk];
        bf8 a1 = *(const bf8*)&As[wm + 16 + fr][fk];
        bf8 b0 = *(const bf8*)&Bs[wn + fr][fk];
        bf8 b1 = *(const bf8*)&Bs[wn + 16 + fr][fk];
        acc[0][0] = __builtin_amdgcn_mfma_f32_16x16x32_bf16(a0, b0, acc[0][0], 0, 0, 0);
        acc[0][1] = __builtin_amdgcn_mfma_f32_16x16x32_bf16(a0, b1, acc[0][1], 0, 0, 0);
        acc[1][0] = __builtin_amdgcn_mfma_f32_16x16x32_bf16(a1, b0, acc[1][0], 0, 0, 0);
        acc[1][1] = __builtin_amdgcn_mfma_f32_16x16x32_bf16(a1, b1, acc[1][1], 0, 0, 0);
        __syncthreads();
    }
    // phase 2: h[d], K = 256
    int d = n0 >> 10;
    const short* A2 = hb + d * B_ * H_;
    for (int kc = 0; kc < H_ / 32; kc++) {
        int k = kc * 32 + cg;
        *(int4*)&As[r][cg] = *(const int4*)(A2 + b * H_ + k);
        *(int4*)&Bs[r][cg] = *(const int4*)(Whh + (n0 + r) * H_ + k);
        __syncthreads();
        bf8 a0 = *(const bf8*)&As[wm + fr][fk];
        bf8 a1 = *(const bf8*)&As[wm + 16 + fr][fk];
        bf8 b0 = *(const bf8*)&Bs[wn + fr][fk];
        bf8 b1 = *(const bf8*)&Bs[wn + 16 + fr][fk];
        acc[0][0] = __builtin_amdgcn_mfma_f32_16x16x32_bf16(a0, b0, acc[0][0], 0, 0, 0);
        acc[0][1] = __builtin_amdgcn_mfma_f32_16x16x32_bf16(a0, b1, acc[0][1], 0, 0, 0);
        acc[1][0] = __builtin_amdgcn_mfma_f32_16x16x32_bf16(a1, b0, acc[1][0], 0, 0, 0);
        acc[1][1] = __builtin_amdgcn_mfma_f32_16x16x32_bf16(a1, b1, acc[1][1], 0, 0, 0);
        __syncthreads();
    }
    int colb = n0 + wn + (lane & 15);
    int rowb = m0 + wm + (lane >> 4) * 4;
    #pragma unroll
    for (int im = 0; im < 2; im++)
        #pragma unroll
        for (int in = 0; in < 2; in++)
            #pragma unroll
            for (int q = 0; q < 4; q++)
                gates[(rowb + im * 16 + q) * ND_ + colb + in * 16] = acc[im][in][q];
}

// ---------------- LSTM pointwise; writes new h (bf16, into x and hb) and c ----------------
__global__ __launch_bounds__(256) void k_lstm(const float* __restrict__ gates,
                                              const float* __restrict__ bih,
                                              const float* __restrict__ bhh,
                                              const float* __restrict__ ff, int step,
                                              float* __restrict__ c, short* __restrict__ hb,
                                              short* __restrict__ x) {
    int i = blockIdx.x * 256 + threadIdx.x;
    int d = i >> 16, b = (i >> 8) & 255, j = i & 255;
    int gb = b * ND_ + d * G_;
    int bb = d * G_;
    float ig = gates[gb + j]       + bih[bb + j]       + bhh[bb + j];
    float fg = gates[gb + 256 + j] + bih[bb + 256 + j] + bhh[bb + 256 + j];
    float gg = gates[gb + 512 + j] + bih[bb + 512 + j] + bhh[bb + 512 + j];
    float og = gates[gb + 768 + j] + bih[bb + 768 + j] + bhh[bb + 768 + j];
    float cv = c[i];
    float cn = sigm(fg) * cv + sigm(ig) * tanhf(gg);
    float hn = sigm(og) * tanhf(cn);
    c[i] = cn;
    short hv = f2bf(hn);
    hb[i] = hv;
    x[b * KX_ + d * H_ + j] = hv;
    if (d == 0 && j < M_ && step + 1 < FT_)
        x[b * KX_ + E_ + j] = f2bf(ff[(b * FT_ + step + 1) * M_ + j]);
}

// ---------------- fc2: y[b] = b2 + sum relu_z[b,:] . w2 ----------------
__global__ __launch_bounds__(256) void k_fc2(const float* __restrict__ z,
                                             const float* __restrict__ w2,
                                             const float* __restrict__ b2,
                                             float* __restrict__ out, int step) {
    int b = blockIdx.x * 4 + (threadIdx.x >> 6);
    int lane = threadIdx.x & 63;
    const float* zr = z + b * H_;
    float s = zr[lane] * w2[lane] + zr[lane + 64] * w2[lane + 64] +
              zr[lane + 128] * w2[lane + 128] + zr[lane + 192] * w2[lane + 192];
    for (int off = 32; off; off >>= 1) s += __shfl_xor(s, off);
    if (lane == 0) out[b * FT_ + step] = s + b2[0];
}

extern "C" void kernel_launch(void* const* d_in, const int* in_sizes, int n_in,
                              void* d_out, int out_size, void* d_ws, size_t ws_size,
                              hipStream_t stream) {
    (void)in_sizes; (void)n_in; (void)out_size;
    const float* enc_f  = (const float*)d_in[0];
    const float* fhist  = (const float*)d_in[1];
    const float* ff     = (const float*)d_in[3];
    const float* hidden = (const float*)d_in[4];
    const float* cell   = (const float*)d_in[5];
    const float* aW1    = (const float*)d_in[6];
    const float* ab1    = (const float*)d_in[7];
    const float* aW2    = (const float*)d_in[8];
    const float* ab2    = (const float*)d_in[9];
    const float* Wih    = (const float*)d_in[10];
    const float* Whh    = (const float*)d_in[11];
    const float* bih    = (const float*)d_in[12];
    const float* bhh    = (const float*)d_in[13];
    const float* fW1    = (const float*)d_in[14];
    const float* fb1    = (const float*)d_in[15];
    const float* fW2    = (const float*)d_in[16];
    const float* fb2    = (const float*)d_in[17];
    float* out = (float*)d_out;

    char* p = (char*)d_ws;
    auto take = [&](size_t n) { char* r = p; p += (n + 255) & ~(size_t)255; return r; };
    float* alpha = (float*)take(B_ * 24 * 4);
    short* xb    = (short*)take(B_ * KX_ * 2);
    short* hb    = (short*)take(2 * B_ * H_ * 2);
    float* cbuf  = (float*)take(2 * B_ * H_ * 4);
    short* s1    = (short*)take(B_ * T_ * 2);
    float* logit = (float*)take(B_ * T_ * 4);
    float* ctxp  = (float*)take(4 * B_ * E_ * 4);
    float* gates = (float*)take(B_ * ND_ * 4);
    float* z     = (float*)take(B_ * H_ * 4);
    short* W1b   = (short*)take(T_ * KX_ * 2);
    short* W2b   = (short*)take(T_ * T_ * 2);
    short* Wihb  = (short*)take(ND_ * KX_ * 2);
    short* Whhb  = (short*)take(ND_ * H_ * 2);
    short* fW1b  = (short*)take(H_ * E_ * 2);
    short* encb  = (short*)take((size_t)B_ * T_ * E_ * 2);
    size_t full_need = (size_t)(p - (char*)d_ws);
    bool use_encb = ws_size >= full_need;

    k_alpha<<<B_, 64, 0, stream>>>(ff, fhist, alpha);
    k_cast4<<<(T_ * KX_ / 4 + 255) / 256, 256, 0, stream>>>(aW1, W1b, T_ * KX_ / 4);
    k_cast4<<<(T_ * T_ / 4 + 255) / 256, 256, 0, stream>>>(aW2, W2b, T_ * T_ / 4);
    k_cast4<<<(ND_ * KX_ / 4 + 255) / 256, 256, 0, stream>>>(Wih, Wihb, ND_ * KX_ / 4);
    k_cast4<<<(ND_ * H_ / 4 + 255) / 256, 256, 0, stream>>>(Whh, Whhb, ND_ * H_ / 4);
    k_cast4<<<(H_ * E_ / 4 + 255) / 256, 256, 0, stream>>>(fW1, fW1b, H_ * E_ / 4);
    if (use_encb)
        k_cast4<<<(B_ * T_ * E_ / 4 + 255) / 256, 256, 0, stream>>>(enc_f, encb, B_ * T_ * E_ / 4);
    k_init<<<(2 * B_ * H_) / 256, 256, 0, stream>>>(hidden, cell, ff, xb, hb, cbuf);

    for (int step = 0; step < FT_; step++) {
        k_gemm<0><<<dim3(T_ / 64, B_ / 64), 256, 0, stream>>>(xb, KX_, KX_, W1b, ab1, s1, T_);
        k_gemm<1><<<dim3(T_ / 64, B_ / 64), 256, 0, stream>>>(s1, T_, T_, W2b, ab2, logit, T_);
        if (use_encb)
            k_ctx<1><<<B_ * 4, 256, 0, stream>>>(logit, alpha, encb, enc_f, ctxp);
        else
            k_ctx<0><<<B_ * 4, 256, 0, stream>>>(logit, alpha, encb, enc_f, ctxp);
        k_gates<<<dim3(ND_ / 64, B_ / 64), 256, 0, stream>>>(ctxp, ff, step, hb, Wihb, Whhb, gates);
        k_lstm<<<(2 * B_ * H_) / 256, 256, 0, stream>>>(gates, bih, bhh, ff, step, cbuf, hb, xb);
        k_gemm<3><<<dim3(H_ / 64, B_ / 64), 256, 0, stream>>>(xb, KX_, E_, fW1b, fb1, z, H_);
        k_fc2<<<B_ / 4, 256, 0, stream>>>(z, fW2, fb2, out, step);
    }
}